// Round 6
// baseline (272.690 us; speedup 1.0000x reference)
//
#include <hip/hip_runtime.h>
#include <hip/hip_bf16.h>

#define NFREQ 512
#define KDIM  1024   // 2*NFREQ combined (magn || phase)
#define CDIM  1024   // NFFT output channels
#define TDIM  4096
#define BATCH 8
#define NT    16     // K-tiles of 64

typedef __bf16 bf16;
typedef __attribute__((ext_vector_type(8))) __bf16 bf16x8;
typedef __attribute__((ext_vector_type(4))) float f32x4;

__device__ __forceinline__ void gload_lds16(const bf16* g, void* l) {
    __builtin_amdgcn_global_load_lds(
        (const __attribute__((address_space(1))) void*)g,
        (__attribute__((address_space(3))) void*)l, 16, 0, 0);
}

// ---------------- prep: combined, pre-scaled kernel matrix ----------------
__global__ __launch_bounds__(256) void prep_kc(const float* __restrict__ rk,
                                               const float* __restrict__ ik,
                                               bf16* __restrict__ Kc) {
    int idx = blockIdx.x * 256 + threadIdx.x;
    int c = idx >> 10;
    int k = idx & 1023;
    float v = (k < NFREQ) ? rk[c * NFREQ + k] : -ik[c * NFREQ + (k - NFREQ)];
    Kc[idx] = (bf16)(v * (1.0f / 1024.0f));
}

// ---------------- fused GEMM: transpose+cvt folded into B staging ----------------
// out[b][c][t] = sum_k Kc[c][k] * X[b][k][t],  X = [magn ; phase] (f32, t-contig)
// Address math identical to R5 (correctness-verified). Schedule restored to
// R4 depth: A-stages for v+1 all at p0, drained by counted vmcnt(8) at p3;
// B f32 loads double-buffered in regs (bld0/bld1), loaded at p1 of tile v for
// tile v+2, converted+written at p2 of tile v+1 (5 phases of latency cover).
__global__ __launch_bounds__(512, 2) void gemmf(const bf16* __restrict__ Kc,
                                                const float* __restrict__ magn,
                                                const float* __restrict__ phase,
                                                float* __restrict__ out) {
    extern __shared__ __align__(16) char smem[];   // 128 KB: [buf][A 32K | B 32K]

    const int tid = threadIdx.x;
    const int w = tid >> 6;          // wave 0..7
    const int l = tid & 63;

    // R4 decode: bm-sharers of a (b,bn) B-panel land on the same XCD.
    const int x  = blockIdx.x;
    const int bm = x >> 4;           // 0..3  (c tiles of 256)
    const int bn = x & 15;           // 0..15 (t tiles of 256)
    const int b  = blockIdx.y;

    const bf16* Ab = Kc + (size_t)(bm * 256) * KDIM;

    // A staging geometry (gload_lds, wave-uniform dest + lane*16)
    const int srow = ((w >> 2) * 128) + ((w & 3) * 8);
    const int ssub = l >> 3;         // row within 8-row wave chunk

    // fragment-read geometry
    const int wr = w >> 2;           // 0..1 (M)
    const int wc = w & 3;            // 0..3 (N)
    const int fr = l & 15;
    const int l16 = l >> 4;          // 0..3

    // B global bases (per-lane t offset; wave w owns k-octave 8w..8w+7)
    const float* mb = magn + (size_t)b * NFREQ * TDIM + (size_t)(8 * w) * TDIM + bn * 256 + 4 * l;
    const float* pb = phase + (size_t)b * NFREQ * TDIM + (size_t)(8 * w) * TDIM + bn * 256 + 4 * l;

    f32x4 acc[8][4] = {};
    float4 bld0[8], bld1[8];         // named double-buffer (static indexing only)

#define STAGE_A(curb, q, kt) \
    gload_lds16(Ab + (size_t)(srow + (q)*32 + ssub) * KDIM + (kt)*64 \
                   + (((l & 7) ^ ssub ^ (w & 3) ^ ((((q)&1)) << 2)) * 8), \
                smem + (curb)*65536 + (srow + (q)*32) * 128)

#define BLOADM(dst, vn) { \
    const float* s_ = (((vn) < 8) ? mb : pb) + (size_t)(((vn) & 7) * 64) * TDIM; \
    _Pragma("unroll") \
    for (int j = 0; j < 8; j++) dst[j] = *(const float4*)(s_ + (size_t)j * TDIM); }

#define BWRITE(dstB, srcb) { \
    _Pragma("unroll") \
    for (int c = 0; c < 4; c++) { \
        bf16x8 o_; \
        _Pragma("unroll") \
        for (int j = 0; j < 8; j++) o_[j] = (bf16)(((const float*)&srcb[j])[c]); \
        const int t_ = 4 * l + c; \
        const int sw_ = (t_ & 7) ^ ((l >> 1) & 7); \
        *(bf16x8*)((dstB) + t_ * 128 + ((w ^ sw_) * 16)) = o_; } }

    // -------- prologue --------
    // order: A-stages (oldest), bld0 <- tile0, bld1 <- tile1.
    // BWRITE(bld0) gets compiler vmcnt(8): drains A+bld0, leaves bld1 in flight.
    STAGE_A(0, 0, 0); STAGE_A(0, 1, 0); STAGE_A(0, 2, 0); STAGE_A(0, 3, 0);
    BLOADM(bld0, 0);
    BLOADM(bld1, 1);
    BWRITE(smem + 32768, bld0);
    asm volatile("s_waitcnt vmcnt(8)" ::: "memory");    // A staged (older than bld0)
    asm volatile("s_waitcnt lgkmcnt(0)" ::: "memory");  // B writes visible
    __builtin_amdgcn_s_barrier();
    __builtin_amdgcn_sched_barrier(0);

    // tile v: compute from buf CUR=v&1; stage A(v+1)@p0; BLOAD(v+2)->BLDL@p1;
    // BWRITE(v+1 from BLDU)@p2 (BLDU loaded at p1 of v-1); counted vmcnt@p3.
#define TILE(v, CUR, BLDL, BLDU)                                              \
    {                                                                          \
        const char* At = smem + (CUR) * 65536;                                 \
        const char* Bt = At + 32768;                                           \
        char* Bn = smem + ((CUR) ^ 1) * 65536 + 32768;                         \
        bf16x8 ah[8];                                                          \
        _Pragma("unroll")                                                      \
        for (int p = 0; p < 4; p++) {                                          \
            const int ph = p >> 1, pn = p & 1;                                 \
            if (pn == 0) {                                                     \
                _Pragma("unroll")                                              \
                for (int mi = 0; mi < 4; mi++)                                 \
                    _Pragma("unroll")                                          \
                    for (int kk = 0; kk < 2; kk++) {                           \
                        const int M = ph * 4 + mi;                             \
                        const int r = wr * 128 + M * 16 + fr;                  \
                        const int fx = (fr & 7) ^ ((M * 2 + (fr >> 3)) & 7);   \
                        ah[mi * 2 + kk] = *(const bf16x8*)(At + r * 128 + (((kk * 4 + l16) ^ fx) * 16)); \
                    }                                                          \
            }                                                                  \
            bf16x8 bh[2][2];                                                   \
            _Pragma("unroll")                                                  \
            for (int ni = 0; ni < 2; ni++)                                     \
                _Pragma("unroll")                                              \
                for (int kk = 0; kk < 2; kk++) {                               \
                    const int n = pn * 2 + ni;                                 \
                    const int r = wc * 64 + n * 16 + fr;                       \
                    const int fx = (fr & 7) ^ ((n * 2 + (fr >> 3)) & 7);       \
                    bh[ni][kk] = *(const bf16x8*)(Bt + r * 128 + (((kk * 4 + l16) ^ fx) * 16)); \
                }                                                              \
            if (p == 0 && (v) + 1 < NT) {                                      \
                STAGE_A((CUR) ^ 1, 0, (v) + 1); STAGE_A((CUR) ^ 1, 1, (v) + 1);\
                STAGE_A((CUR) ^ 1, 2, (v) + 1); STAGE_A((CUR) ^ 1, 3, (v) + 1);\
            }                                                                  \
            if (p == 1 && (v) + 2 < NT) { BLOADM(BLDL, (v) + 2); }             \
            __builtin_amdgcn_s_barrier();                                      \
            __builtin_amdgcn_s_setprio(1);                                     \
            _Pragma("unroll")                                                  \
            for (int mi = 0; mi < 4; mi++)                                     \
                _Pragma("unroll")                                              \
                for (int ni = 0; ni < 2; ni++)                                 \
                    _Pragma("unroll")                                          \
                    for (int kk = 0; kk < 2; kk++)                             \
                        acc[ph * 4 + mi][pn * 2 + ni] = __builtin_amdgcn_mfma_f32_16x16x32_bf16( \
                            ah[mi * 2 + kk], bh[ni][kk], acc[ph * 4 + mi][pn * 2 + ni], 0, 0, 0); \
            __builtin_amdgcn_s_setprio(0);                                     \
            if (p == 2 && (v) + 1 < NT) { BWRITE(Bn, BLDU); }                  \
            if (p == 3) {                                                      \
                if ((v) + 2 < NT) { asm volatile("s_waitcnt vmcnt(8)" ::: "memory"); } \
                else              { asm volatile("s_waitcnt vmcnt(0)" ::: "memory"); } \
                asm volatile("s_waitcnt lgkmcnt(0)" ::: "memory");             \
            }                                                                  \
            __builtin_amdgcn_s_barrier();                                      \
            __builtin_amdgcn_sched_barrier(0);                                 \
        }                                                                      \
    }

    for (int vv = 0; vv < NT; vv += 2) {
        TILE(vv,     0, bld0, bld1)
        TILE(vv + 1, 1, bld1, bld0)
    }
#undef TILE
#undef STAGE_A
#undef BLOADM
#undef BWRITE

    // epilogue: C/D layout col = lane&15, row = (lane>>4)*4 + j
    const int cr = l16 * 4;
    const int cc = fr;
    float* obase = out + ((size_t)b * CDIM + bm * 256 + wr * 128) * TDIM + bn * 256 + wc * 64;
#pragma unroll
    for (int m = 0; m < 8; m++)
#pragma unroll
        for (int n = 0; n < 4; n++)
#pragma unroll
            for (int j = 0; j < 4; j++)
                obase[(size_t)(m * 16 + cr + j) * TDIM + n * 16 + cc] = acc[m][n][j];
}

// ---------------- fallback (ws too small): naive f32 ----------------
__global__ __launch_bounds__(256) void naive_kernel(const float* __restrict__ m,
                                                    const float* __restrict__ p,
                                                    const float* __restrict__ rk,
                                                    const float* __restrict__ ik,
                                                    float* __restrict__ out) {
    size_t idx = (size_t)blockIdx.x * 256 + threadIdx.x;
    int t = idx & 4095;
    size_t r = idx >> 12;
    int c = (int)(r & 1023);
    int b = (int)(r >> 10);
    float acc = 0.f;
    for (int f = 0; f < NFREQ; f++) {
        acc += rk[c * NFREQ + f] * m[((size_t)b * NFREQ + f) * TDIM + t]
             - ik[c * NFREQ + f] * p[((size_t)b * NFREQ + f) * TDIM + t];
    }
    out[idx] = acc * (1.0f / 1024.0f);
}

extern "C" void kernel_launch(void* const* d_in, const int* in_sizes, int n_in,
                              void* d_out, int out_size, void* d_ws, size_t ws_size,
                              hipStream_t stream) {
    const float* magn  = (const float*)d_in[0];
    const float* phase = (const float*)d_in[1];
    const float* rk    = (const float*)d_in[2];
    const float* ik    = (const float*)d_in[3];
    float* out = (float*)d_out;

    const size_t kc_bytes = (size_t)CDIM * KDIM * sizeof(bf16);   // 2 MB
    if (ws_size < kc_bytes) {
        naive_kernel<<<(CDIM * TDIM * BATCH) / 256, 256, 0, stream>>>(magn, phase, rk, ik, out);
        return;
    }

    bf16* Kc = (bf16*)d_ws;

    (void)hipFuncSetAttribute((const void*)gemmf,
                              hipFuncAttributeMaxDynamicSharedMemorySize, 131072);

    prep_kc<<<(CDIM * KDIM) / 256, 256, 0, stream>>>(rk, ik, Kc);
    gemmf<<<dim3(64, BATCH), 512, 131072, stream>>>(Kc, magn, phase, out);
}

// Round 7
// 136.558 us; speedup vs baseline: 1.9969x; 1.9969x over previous
//
#include <hip/hip_runtime.h>
#include <hip/hip_bf16.h>

#define NFREQ 512
#define KDIM  1024   // 2*NFREQ combined (magn || phase)
#define CDIM  1024   // NFFT output channels
#define TDIM  4096
#define BATCH 8
#define NT    16     // K-tiles of 64

// LDS geometry: per buffer A 32768 B (128-B rows) + B 36864 B (144-B rows)
#define ABYTES 32768
#define BSTR   144
#define BUFSZ  (ABYTES + 256 * BSTR)   // 69632
#define LDS_TOTAL (2 * BUFSZ)          // 139264

typedef __bf16 bf16;
typedef __attribute__((ext_vector_type(8))) __bf16 bf16x8;
typedef __attribute__((ext_vector_type(4))) float f32x4;

__device__ __forceinline__ void gload_lds16(const bf16* g, void* l) {
    __builtin_amdgcn_global_load_lds(
        (const __attribute__((address_space(1))) void*)g,
        (__attribute__((address_space(3))) void*)l, 16, 0, 0);
}

// ---------------- prep: combined, pre-scaled kernel matrix ----------------
__global__ __launch_bounds__(256) void prep_kc(const float* __restrict__ rk,
                                               const float* __restrict__ ik,
                                               bf16* __restrict__ Kc) {
    int idx = blockIdx.x * 256 + threadIdx.x;
    int c = idx >> 10;
    int k = idx & 1023;
    float v = (k < NFREQ) ? rk[c * NFREQ + k] : -ik[c * NFREQ + (k - NFREQ)];
    Kc[idx] = (bf16)(v * (1.0f / 1024.0f));
}

// ---------------- fused GEMM: transpose+cvt folded into B staging ----------------
// out[b][c][t] = sum_k Kc[c][k] * X[b][k][t],  X = [magn ; phase] (f32, t-contig)
// A: R4-verified gload_lds path, 128-B rows, swizzle g(r)=(r&7)^((r>>3)&7) via
//    pre-swizzled global source. B: reg-staged f32 -> cvt -> swizzled
//    ds_write_b128 into 144-B-stride rows (bank spread: (4r+4s)%32).
// Pipeline: A(v+1) staged at p0(v), drained by counted vmcnt(8) at p3(v).
//           bld loaded at p3(v) for tile v+2, cvt+written at p3(v+1).
__global__ __launch_bounds__(512, 2) void gemmf(const bf16* __restrict__ Kc,
                                                const float* __restrict__ magn,
                                                const float* __restrict__ phase,
                                                float* __restrict__ out) {
    extern __shared__ __align__(16) char smem[];

    const int tid = threadIdx.x;
    const int w = tid >> 6;          // wave 0..7
    const int l = tid & 63;

    // R4 decode: the 4 bm-sharers of a (b,bn) B-panel land on the same XCD.
    const int x  = blockIdx.x;
    const int bm = x >> 4;           // 0..3  (c tiles of 256)
    const int bn = x & 15;           // 0..15 (t tiles of 256)
    const int b  = blockIdx.y;

    const bf16* Ab = Kc + (size_t)(bm * 256) * KDIM;

    // A staging geometry (gload_lds, wave-uniform dest + lane*16)
    const int srow = ((w >> 2) * 128) + ((w & 3) * 8);
    const int ssub = l >> 3;         // row within 8-row wave chunk

    // fragment-read geometry
    const int wr = w >> 2;           // 0..1 (M)
    const int wc = w & 3;            // 0..3 (N)
    const int fr = l & 15;
    const int l16 = l >> 4;          // 0..3

    // B global bases (wave w owns k-octave 8w..8w+7; lane covers 4 t-values)
    const float* mb = magn + (size_t)b * NFREQ * TDIM + (size_t)(8 * w) * TDIM + bn * 256 + 4 * l;
    const float* pb = phase + (size_t)b * NFREQ * TDIM + (size_t)(8 * w) * TDIM + bn * 256 + 4 * l;

    f32x4 acc[8][4] = {};
    float4 bld[8];                   // single in-flight B staging buffer

#define STAGE_A(curb, q, kt) \
    gload_lds16(Ab + (size_t)(srow + (q)*32 + ssub) * KDIM + (kt)*64 \
                   + (((l & 7) ^ ssub ^ (w & 3) ^ ((((q)&1)) << 2)) * 8), \
                smem + (curb)*BUFSZ + (srow + (q)*32) * 128)

#define BLOADM(vn) { \
    const float* s_ = (((vn) < 8) ? mb : pb) + (size_t)(((vn) & 7) * 64) * TDIM; \
    _Pragma("unroll") \
    for (int j = 0; j < 8; j++) bld[j] = *(const float4*)(s_ + (size_t)j * TDIM); }

#define BWRITE(dstB) { \
    _Pragma("unroll") \
    for (int c = 0; c < 4; c++) { \
        bf16x8 o_; \
        _Pragma("unroll") \
        for (int j = 0; j < 8; j++) o_[j] = (bf16)(((const float*)&bld[j])[c]); \
        const int t_ = 4 * l + c; \
        const int g_ = (t_ & 7) ^ ((t_ >> 3) & 7); \
        *(bf16x8*)((dstB) + t_ * BSTR + ((w ^ g_) * 16)) = o_; } }

    // -------- prologue --------
    BLOADM(0);                                   // bld <- tile0 (oldest, 8 ops)
    STAGE_A(0, 0, 0); STAGE_A(0, 1, 0); STAGE_A(0, 2, 0); STAGE_A(0, 3, 0);
    BWRITE(smem + ABYTES);                       // compiler: vmcnt(4) (drains bld)
    BLOADM(1);                                   // bld <- tile1
    asm volatile("s_waitcnt vmcnt(8)" ::: "memory");    // drain A(t0), keep bld
    asm volatile("s_waitcnt lgkmcnt(0)" ::: "memory");  // B writes visible
    __builtin_amdgcn_s_barrier();
    __builtin_amdgcn_sched_barrier(0);

    for (int v = 0; v < NT; ++v) {
        const int cur = v & 1;
        const char* At = smem + cur * BUFSZ;
        const char* Bt = At + ABYTES;
        char* Bn = smem + (cur ^ 1) * BUFSZ + ABYTES;
        bf16x8 ah[8];                // A half: mi 0..3 x kk 0..1, held 2 phases

#pragma unroll
        for (int p = 0; p < 4; p++) {
            const int ph = p >> 1;   // m-half
            const int pn = p & 1;    // n-half

            if (pn == 0) {           // (re)load A-half at p0, p2
#pragma unroll
                for (int mi = 0; mi < 4; mi++)
#pragma unroll
                    for (int kk = 0; kk < 2; kk++) {
                        const int M = ph * 4 + mi;
                        const int r = wr * 128 + M * 16 + fr;
                        const int fx = (fr & 7) ^ ((M * 2 + (fr >> 3)) & 7);
                        ah[mi * 2 + kk] = *(const bf16x8*)(At + r * 128 + (((kk * 4 + l16) ^ fx) * 16));
                    }
            }
            bf16x8 bh[2][2];         // B half: re-read every phase
#pragma unroll
            for (int ni = 0; ni < 2; ni++)
#pragma unroll
                for (int kk = 0; kk < 2; kk++) {
                    const int n = pn * 2 + ni;
                    const int r = wc * 64 + n * 16 + fr;
                    const int fx = (fr & 7) ^ ((n * 2 + (fr >> 3)) & 7);
                    bh[ni][kk] = *(const bf16x8*)(Bt + r * BSTR + (((kk * 4 + l16) ^ fx) * 16));
                }

            if (p == 0 && v + 1 < NT) {          // all A-stages for v+1 at p0
                STAGE_A(cur ^ 1, 0, v + 1); STAGE_A(cur ^ 1, 1, v + 1);
                STAGE_A(cur ^ 1, 2, v + 1); STAGE_A(cur ^ 1, 3, v + 1);
            }

            __builtin_amdgcn_s_barrier();
            __builtin_amdgcn_s_setprio(1);
#pragma unroll
            for (int mi = 0; mi < 4; mi++)
#pragma unroll
                for (int ni = 0; ni < 2; ni++)
#pragma unroll
                    for (int kk = 0; kk < 2; kk++)
                        acc[ph * 4 + mi][pn * 2 + ni] = __builtin_amdgcn_mfma_f32_16x16x32_bf16(
                            ah[mi * 2 + kk], bh[ni][kk], acc[ph * 4 + mi][pn * 2 + ni], 0, 0, 0);
            __builtin_amdgcn_s_setprio(0);

            if (p == 3) {
                if (v + 1 < NT) BWRITE(Bn);      // cvt+write B(v+1); auto vmcnt(4)
                if (v + 2 < NT) {
                    BLOADM(v + 2);               // refill bld (WAR handled by regalloc)
                    asm volatile("s_waitcnt vmcnt(8)" ::: "memory");  // drain A(v+1)
                } else {
                    asm volatile("s_waitcnt vmcnt(0)" ::: "memory");
                }
                asm volatile("s_waitcnt lgkmcnt(0)" ::: "memory");    // B writes done
            }
            __builtin_amdgcn_s_barrier();
            __builtin_amdgcn_sched_barrier(0);
        }
    }
#undef STAGE_A
#undef BLOADM
#undef BWRITE

    // epilogue: C/D layout col = lane&15, row = (lane>>4)*4 + j
    const int cr = l16 * 4;
    const int cc = fr;
    float* obase = out + ((size_t)b * CDIM + bm * 256 + wr * 128) * TDIM + bn * 256 + wc * 64;
#pragma unroll
    for (int m = 0; m < 8; m++)
#pragma unroll
        for (int n = 0; n < 4; n++)
#pragma unroll
            for (int j = 0; j < 4; j++)
                obase[(size_t)(m * 16 + cr + j) * TDIM + n * 16 + cc] = acc[m][n][j];
}

// ---------------- fallback (ws too small): naive f32 ----------------
__global__ __launch_bounds__(256) void naive_kernel(const float* __restrict__ m,
                                                    const float* __restrict__ p,
                                                    const float* __restrict__ rk,
                                                    const float* __restrict__ ik,
                                                    float* __restrict__ out) {
    size_t idx = (size_t)blockIdx.x * 256 + threadIdx.x;
    int t = idx & 4095;
    size_t r = idx >> 12;
    int c = (int)(r & 1023);
    int b = (int)(r >> 10);
    float acc = 0.f;
    for (int f = 0; f < NFREQ; f++) {
        acc += rk[c * NFREQ + f] * m[((size_t)b * NFREQ + f) * TDIM + t]
             - ik[c * NFREQ + f] * p[((size_t)b * NFREQ + f) * TDIM + t];
    }
    out[idx] = acc * (1.0f / 1024.0f);
}

extern "C" void kernel_launch(void* const* d_in, const int* in_sizes, int n_in,
                              void* d_out, int out_size, void* d_ws, size_t ws_size,
                              hipStream_t stream) {
    const float* magn  = (const float*)d_in[0];
    const float* phase = (const float*)d_in[1];
    const float* rk    = (const float*)d_in[2];
    const float* ik    = (const float*)d_in[3];
    float* out = (float*)d_out;

    const size_t kc_bytes = (size_t)CDIM * KDIM * sizeof(bf16);   // 2 MB
    if (ws_size < kc_bytes) {
        naive_kernel<<<(CDIM * TDIM * BATCH) / 256, 256, 0, stream>>>(magn, phase, rk, ik, out);
        return;
    }

    bf16* Kc = (bf16*)d_ws;

    (void)hipFuncSetAttribute((const void*)gemmf,
                              hipFuncAttributeMaxDynamicSharedMemorySize, LDS_TOTAL);

    prep_kc<<<(CDIM * KDIM) / 256, 256, 0, stream>>>(rk, ik, Kc);
    gemmf<<<dim3(64, BATCH), 512, LDS_TOTAL, stream>>>(Kc, magn, phase, out);
}

// Round 8
// 123.647 us; speedup vs baseline: 2.2054x; 1.1044x over previous
//
#include <hip/hip_runtime.h>
#include <hip/hip_bf16.h>

#define NFREQ 512
#define KDIM  1024   // 2*NFREQ combined (magn || phase)
#define CDIM  1024   // NFFT output channels
#define TDIM  4096
#define BATCH 8
#define NT    16     // K-tiles of 64

#define ABYTES 32768
#define BUFSZ  65536
#define LDS_TOTAL 131072

typedef __bf16 bf16;
typedef __attribute__((ext_vector_type(8))) __bf16 bf16x8;
typedef __attribute__((ext_vector_type(4))) float f32x4;

__device__ __forceinline__ void gload_lds16(const bf16* g, void* l) {
    __builtin_amdgcn_global_load_lds(
        (const __attribute__((address_space(1))) void*)g,
        (__attribute__((address_space(3))) void*)l, 16, 0, 0);
}

// ---------------- prep: combined, pre-scaled kernel matrix ----------------
__global__ __launch_bounds__(256) void prep_kc(const float* __restrict__ rk,
                                               const float* __restrict__ ik,
                                               bf16* __restrict__ Kc) {
    int idx = blockIdx.x * 256 + threadIdx.x;
    int c = idx >> 10;
    int k = idx & 1023;
    float v = (k < NFREQ) ? rk[c * NFREQ + k] : -ik[c * NFREQ + (k - NFREQ)];
    Kc[idx] = (bf16)(v * (1.0f / 1024.0f));
}

// ---------------- fused GEMM: transpose+cvt folded into B staging ----------------
// out[b][c][t] = sum_k Kc[c][k] * X[b][k][t],  X = [magn ; phase] (f32, t-contig)
// A: exact R4 pattern (verified 0-conflict): gload_lds, 128-B rows,
//    g_A(r) = r&7 via source scol, read fx = fr&7.
// B: 128-B rows, g_B(t) = (t&7) ^ ((t>>3)&7) ^ (((t>>6)&3)<<1).
//    The t>>6 term spreads the 4 sixteen-lane write groups (t=4l+c) across
//    XOR-distinct bank groups; each 8-lane octet covers all 8 groups once.
// Schedule identical to R7: A(v+1)@p0 drained by counted vmcnt(8)@p3;
// bld loaded @p3(v) for v+2, cvt+ds_write @p3(v+1) (4-phase latency cover).
__global__ __launch_bounds__(512, 2) void gemmf(const bf16* __restrict__ Kc,
                                                const float* __restrict__ magn,
                                                const float* __restrict__ phase,
                                                float* __restrict__ out) {
    extern __shared__ __align__(16) char smem[];

    const int tid = threadIdx.x;
    const int w = tid >> 6;          // wave 0..7
    const int l = tid & 63;

    // R4 decode: the 4 bm-sharers of a (b,bn) B-panel land on the same XCD.
    const int x  = blockIdx.x;
    const int bm = x >> 4;           // 0..3  (c tiles of 256)
    const int bn = x & 15;           // 0..15 (t tiles of 256)
    const int b  = blockIdx.y;

    const bf16* Ab = Kc + (size_t)(bm * 256) * KDIM;

    // A staging geometry (gload_lds, wave-uniform dest + lane*16)
    const int srow = ((w >> 2) * 128) + ((w & 3) * 8);
    const int ssub = l >> 3;         // row within 8-row wave chunk
    const int scol = ((l & 7) ^ ssub) * 8;   // R4 source swizzle (g_A = r&7)

    // fragment-read geometry
    const int wr = w >> 2;           // 0..1 (M)
    const int wc = w & 3;            // 0..3 (N)
    const int fr = l & 15;
    const int l16 = l >> 4;          // 0..3
    const int fxA = fr & 7;          // A read swizzle (g_A = r&7)

    // B global bases (wave w owns k-octave 8w..8w+7; lane covers 4 t-values)
    const float* mb = magn + (size_t)b * NFREQ * TDIM + (size_t)(8 * w) * TDIM + bn * 256 + 4 * l;
    const float* pb = phase + (size_t)b * NFREQ * TDIM + (size_t)(8 * w) * TDIM + bn * 256 + 4 * l;

    // precomputed B write offsets (v-independent): t_ = 4l+c, pos = w ^ g_B(t_)
    int bwoff[4];
#pragma unroll
    for (int c = 0; c < 4; c++) {
        const int t_ = 4 * l + c;
        const int g_ = (t_ & 7) ^ ((t_ >> 3) & 7) ^ (((t_ >> 6) & 3) << 1);
        bwoff[c] = t_ * 128 + ((w ^ g_) * 16);
    }

    f32x4 acc[8][4] = {};
    float4 bld[8];                   // single in-flight B staging buffer

#define STAGE_A(curb, q, kt) \
    gload_lds16(Ab + (size_t)(srow + (q)*32 + ssub) * KDIM + (kt)*64 + scol, \
                smem + (curb)*BUFSZ + (srow + (q)*32) * 128)

#define BLOADM(vn) { \
    const float* s_ = (((vn) < 8) ? mb : pb) + (size_t)(((vn) & 7) * 64) * TDIM; \
    _Pragma("unroll") \
    for (int j = 0; j < 8; j++) bld[j] = *(const float4*)(s_ + (size_t)j * TDIM); }

#define BWRITE(dstB) { \
    _Pragma("unroll") \
    for (int c = 0; c < 4; c++) { \
        bf16x8 o_; \
        _Pragma("unroll") \
        for (int j = 0; j < 8; j++) o_[j] = (bf16)(((const float*)&bld[j])[c]); \
        *(bf16x8*)((dstB) + bwoff[c]) = o_; } }

    // -------- prologue --------
    BLOADM(0);                                   // bld <- tile0 (oldest, 8 ops)
    STAGE_A(0, 0, 0); STAGE_A(0, 1, 0); STAGE_A(0, 2, 0); STAGE_A(0, 3, 0);
    BWRITE(smem + ABYTES);                       // compiler: vmcnt(4) (drains bld)
    BLOADM(1);                                   // bld <- tile1
    asm volatile("s_waitcnt vmcnt(8)" ::: "memory");    // drain A(t0), keep bld
    asm volatile("s_waitcnt lgkmcnt(0)" ::: "memory");  // B writes visible
    __builtin_amdgcn_s_barrier();
    __builtin_amdgcn_sched_barrier(0);

    for (int v = 0; v < NT; ++v) {
        const int cur = v & 1;
        const char* At = smem + cur * BUFSZ;
        const char* Bt = At + ABYTES;
        char* Bn = smem + (cur ^ 1) * BUFSZ + ABYTES;
        bf16x8 ah[8];                // A half: mi 0..3 x kk 0..1, held 2 phases

#pragma unroll
        for (int p = 0; p < 4; p++) {
            const int ph = p >> 1;   // m-half
            const int pn = p & 1;    // n-half

            if (pn == 0) {           // (re)load A-half at p0, p2
#pragma unroll
                for (int mi = 0; mi < 4; mi++)
#pragma unroll
                    for (int kk = 0; kk < 2; kk++) {
                        const int M = ph * 4 + mi;
                        const int r = wr * 128 + M * 16 + fr;
                        ah[mi * 2 + kk] = *(const bf16x8*)(At + r * 128 + (((kk * 4 + l16) ^ fxA) * 16));
                    }
            }
            bf16x8 bh[2][2];         // B half: re-read every phase
#pragma unroll
            for (int ni = 0; ni < 2; ni++)
#pragma unroll
                for (int kk = 0; kk < 2; kk++) {
                    const int n = pn * 2 + ni;
                    const int r = wc * 64 + n * 16 + fr;
                    const int fxB = (fr & 7) ^ ((n * 2 + (fr >> 3)) & 7) ^ (wc << 1);
                    bh[ni][kk] = *(const bf16x8*)(Bt + r * 128 + (((kk * 4 + l16) ^ fxB) * 16));
                }

            if (p == 0 && v + 1 < NT) {          // all A-stages for v+1 at p0
                STAGE_A(cur ^ 1, 0, v + 1); STAGE_A(cur ^ 1, 1, v + 1);
                STAGE_A(cur ^ 1, 2, v + 1); STAGE_A(cur ^ 1, 3, v + 1);
            }

            __builtin_amdgcn_s_barrier();
            __builtin_amdgcn_s_setprio(1);
#pragma unroll
            for (int mi = 0; mi < 4; mi++)
#pragma unroll
                for (int ni = 0; ni < 2; ni++)
#pragma unroll
                    for (int kk = 0; kk < 2; kk++)
                        acc[ph * 4 + mi][pn * 2 + ni] = __builtin_amdgcn_mfma_f32_16x16x32_bf16(
                            ah[mi * 2 + kk], bh[ni][kk], acc[ph * 4 + mi][pn * 2 + ni], 0, 0, 0);
            __builtin_amdgcn_s_setprio(0);

            if (p == 3) {
                if (v + 1 < NT) BWRITE(Bn);      // cvt+write B(v+1); auto vmcnt(4)
                if (v + 2 < NT) {
                    BLOADM(v + 2);               // refill bld
                    asm volatile("s_waitcnt vmcnt(8)" ::: "memory");  // drain A(v+1)
                } else {
                    asm volatile("s_waitcnt vmcnt(0)" ::: "memory");
                }
                asm volatile("s_waitcnt lgkmcnt(0)" ::: "memory");    // B writes done
            }
            __builtin_amdgcn_s_barrier();
            __builtin_amdgcn_sched_barrier(0);
        }
    }
#undef STAGE_A
#undef BLOADM
#undef BWRITE

    // epilogue: C/D layout col = lane&15, row = (lane>>4)*4 + j
    const int cr = l16 * 4;
    const int cc = fr;
    float* obase = out + ((size_t)b * CDIM + bm * 256 + wr * 128) * TDIM + bn * 256 + wc * 64;
#pragma unroll
    for (int m = 0; m < 8; m++)
#pragma unroll
        for (int n = 0; n < 4; n++)
#pragma unroll
            for (int j = 0; j < 4; j++)
                obase[(size_t)(m * 16 + cr + j) * TDIM + n * 16 + cc] = acc[m][n][j];
}

// ---------------- fallback (ws too small): naive f32 ----------------
__global__ __launch_bounds__(256) void naive_kernel(const float* __restrict__ m,
                                                    const float* __restrict__ p,
                                                    const float* __restrict__ rk,
                                                    const float* __restrict__ ik,
                                                    float* __restrict__ out) {
    size_t idx = (size_t)blockIdx.x * 256 + threadIdx.x;
    int t = idx & 4095;
    size_t r = idx >> 12;
    int c = (int)(r & 1023);
    int b = (int)(r >> 10);
    float acc = 0.f;
    for (int f = 0; f < NFREQ; f++) {
        acc += rk[c * NFREQ + f] * m[((size_t)b * NFREQ + f) * TDIM + t]
             - ik[c * NFREQ + f] * p[((size_t)b * NFREQ + f) * TDIM + t];
    }
    out[idx] = acc * (1.0f / 1024.0f);
}

extern "C" void kernel_launch(void* const* d_in, const int* in_sizes, int n_in,
                              void* d_out, int out_size, void* d_ws, size_t ws_size,
                              hipStream_t stream) {
    const float* magn  = (const float*)d_in[0];
    const float* phase = (const float*)d_in[1];
    const float* rk    = (const float*)d_in[2];
    const float* ik    = (const float*)d_in[3];
    float* out = (float*)d_out;

    const size_t kc_bytes = (size_t)CDIM * KDIM * sizeof(bf16);   // 2 MB
    if (ws_size < kc_bytes) {
        naive_kernel<<<(CDIM * TDIM * BATCH) / 256, 256, 0, stream>>>(magn, phase, rk, ik, out);
        return;
    }

    bf16* Kc = (bf16*)d_ws;

    (void)hipFuncSetAttribute((const void*)gemmf,
                              hipFuncAttributeMaxDynamicSharedMemorySize, LDS_TOTAL);

    prep_kc<<<(CDIM * KDIM) / 256, 256, 0, stream>>>(rk, ik, Kc);
    gemmf<<<dim3(64, BATCH), 512, LDS_TOTAL, stream>>>(Kc, magn, phase, out);
}